// Round 11
// baseline (196.754 us; speedup 1.0000x reference)
//
#include <hip/hip_runtime.h>

#define DD 1280
#define PP 8960
#define NK 17
#define NCTX 4014080   // B*G*G*D = 64*49*1280
#define NW   8192000   // S*D*D = 5*1280*1280
#define NBLK 2240      // k_dots blocks (4 samples each)

typedef __attribute__((ext_vector_type(8))) short bf16x8;
typedef __attribute__((ext_vector_type(4))) float f32x4;
typedef __attribute__((ext_vector_type(2))) float f32x2;
typedef unsigned short u16;
typedef unsigned char u8;

__device__ __forceinline__ u16 f2bf(float f) {
  union { float f; unsigned u; } v; v.f = f;
  unsigned r = v.u + 0x7fffu + ((v.u >> 16) & 1u);  // RNE
  return (u16)(r >> 16);
}
__device__ __forceinline__ float bf2f(u16 h) {
  union { unsigned u; float f; } v; v.u = ((unsigned)h) << 16;
  return v.f;
}

__device__ __forceinline__ void gload16(const u16* g, const u16* l) {
  __builtin_amdgcn_global_load_lds(
      (const __attribute__((address_space(1))) unsigned*)g,
      (__attribute__((address_space(3))) unsigned*)l, 16, 0, 0);
}

// ---------------- cvt1: ctx->bf16 | W->bf16, + zero lookback counter ----------------
// grid = 3920 (ctx) + 8000 (W) = 11920 blocks.
__global__ __launch_bounds__(256) void k_cvt(const float* __restrict__ ctx,
                                             const float* __restrict__ Ww,
                                             u16* __restrict__ ctx_bf,
                                             u16* __restrict__ W_bf,
                                             unsigned* __restrict__ cnt) {
  const int b = blockIdx.x;
  if (b == 0 && threadIdx.x == 0) *cnt = 0u;   // visible to k_dots (2 kernel boundaries)
  const float* src; u16* dst; int i;
  if (b < 3920) { src = ctx; dst = ctx_bf; i = (b * 256 + threadIdx.x) * 4; }
  else          { src = Ww;  dst = W_bf;   i = ((b - 3920) * 256 + threadIdx.x) * 4; }
  float4 v = *reinterpret_cast<const float4*>(src + i);
  ushort4 o;
  o.x = f2bf(v.x); o.y = f2bf(v.y); o.z = f2bf(v.z); o.w = f2bf(v.w);
  *reinterpret_cast<ushort4*>(dst + i) = o;
}

// ---------------- gemm (R8-exact, blocks 0..709) + enc->fp8 cvt (blocks 710..4629) ----------------
// gemm: 128x128, BK=32, counted-vmcnt double-buffer (verified R8 structure).
// enc-cvt blocks are BW-bound and co-resident with the latency-bound gemm -> hidden.
__global__ __launch_bounds__(256) void k_gemm(const u16* __restrict__ ctx,
                                              const u16* __restrict__ W,
                                              const float* __restrict__ Wb,
                                              const int* __restrict__ cidx,
                                              u16* __restrict__ pred,
                                              const float* __restrict__ enc,
                                              u8* __restrict__ enc_f8) {
  // SM layout (u16): A buf b = [b*4096, +4096) ; B buf b = [8192 + b*4096, +4096)
  // epilogue Csm wave w = [w*4352, +4352)
  __shared__ u16 SM[17408];

  if (blockIdx.x >= 710) {               // ---- enc -> fp8 e4m3 (OCP), RNE ----
    const int i = ((blockIdx.x - 710) * 256 + threadIdx.x) * 4;
    float4 v = *reinterpret_cast<const float4*>(enc + i);
    unsigned u = __builtin_amdgcn_cvt_pk_fp8_f32(v.x, v.y, 0u, false);
    u = __builtin_amdgcn_cvt_pk_fp8_f32(v.z, v.w, u, true);
    *reinterpret_cast<unsigned*>(enc_f8 + i) = u;
    return;
  }

  const int id  = blockIdx.x;            // 0..709, bijective XCD swizzle (m204)
  const int xcd = id & 7, pos = id >> 3;
  const int wgid = (xcd < 6) ? (xcd * 89 + pos) : (534 + (xcd - 6) * 88 + pos);
  const int bx = wgid / 10;
  const int by = wgid - bx * 10;

  int s, mt0, off, mend;
  if (bx < 21)      { s = 0; mt0 = 0;  off = 0;    mend = 2688; }
  else if (bx < 39) { s = 1; mt0 = 21; off = 2688; mend = 4928; }
  else if (bx < 53) { s = 2; mt0 = 39; off = 4928; mend = 6720; }
  else if (bx < 64) { s = 3; mt0 = 53; off = 6720; mend = 8064; }
  else              { s = 4; mt0 = 64; off = 8064; mend = 8960; }
  const int m0 = off + (bx - mt0) * 128;
  const int n0 = by * 128;

  const int t = threadIdx.x;
  const int lane = t & 63, wid = t >> 6;
  const int wr = wid >> 1, wc = wid & 1;
  const int lr = lane & 15, kq = lane >> 4;

  // staging: 512 slots of 16B per tile; slot = g*256 + t; row = slot>>2, chunk = slot&3
  const int r0s = t >> 2, c0 = t & 3;
  const int r1s = 64 + r0s;
  const int cs0 = c0 ^ ((r0s >> 1) & 3);
  const int cs1 = c0 ^ ((r1s >> 1) & 3);
  int ar0 = m0 + r0s; if (ar0 > mend - 1) ar0 = mend - 1;
  int ar1 = m0 + r1s; if (ar1 > mend - 1) ar1 = mend - 1;
  const u16* aptr0 = ctx + (size_t)cidx[ar0] * DD + cs0 * 8;
  const u16* aptr1 = ctx + (size_t)cidx[ar1] * DD + cs1 * 8;
  const u16* bbase = W + (size_t)s * DD * DD;
  const u16* bptr0 = bbase + (size_t)(n0 + r0s) * DD + cs0 * 8;
  const u16* bptr1 = bbase + (size_t)(n0 + r1s) * DD + cs1 * 8;
  const int sl0 = wid * 512;             // wave-uniform u16 offset within a buffer
  const int sl1 = 2048 + wid * 512;

  f32x4 acc[4][4];
  #pragma unroll
  for (int i = 0; i < 4; ++i)
    #pragma unroll
    for (int j = 0; j < 4; ++j)
      acc[i][j] = (f32x4){0.f, 0.f, 0.f, 0.f};

  // loop-invariant ds_read offsets (u16 units within one buffer)
  int aoff[4], boff[4];
  #pragma unroll
  for (int mi = 0; mi < 4; ++mi) {
    const int ra = wr * 64 + mi * 16 + lr;
    aoff[mi] = ra * 32 + (kq ^ ((ra >> 1) & 3)) * 8;
  }
  #pragma unroll
  for (int ni = 0; ni < 4; ++ni) {
    const int rb = wc * 64 + ni * 16 + lr;
    boff[ni] = rb * 32 + (kq ^ ((rb >> 1) & 3)) * 8;
  }

  // prologue: stage tile 0 into buf 0
  gload16(aptr0, SM + sl0); gload16(aptr1, SM + sl1);
  gload16(bptr0, SM + 8192 + sl0); gload16(bptr1, SM + 8192 + sl1);

  #pragma unroll 2
  for (int kt = 0; kt < 40; ++kt) {
    const int cur = kt & 1;
    if (kt < 39) {
      const int k0 = (kt + 1) * 32;
      const int d = (cur ^ 1) * 4096;
      gload16(aptr0 + k0, SM + d + sl0); gload16(aptr1 + k0, SM + d + sl1);
      gload16(bptr0 + k0, SM + 8192 + d + sl0); gload16(bptr1 + k0, SM + 8192 + d + sl1);
      asm volatile("s_waitcnt vmcnt(4)" ::: "memory");   // tile kt landed; kt+1 in flight
    } else {
      asm volatile("s_waitcnt vmcnt(0)" ::: "memory");
    }
    __builtin_amdgcn_s_barrier();        // all waves: tile kt visible
    __builtin_amdgcn_sched_barrier(0);

    const u16* ab = SM + cur * 4096;
    const u16* bb = SM + 8192 + cur * 4096;
    bf16x8 af[4], bf[4];
    #pragma unroll
    for (int mi = 0; mi < 4; ++mi)
      af[mi] = *reinterpret_cast<const bf16x8*>(ab + aoff[mi]);
    #pragma unroll
    for (int ni = 0; ni < 4; ++ni)
      bf[ni] = *reinterpret_cast<const bf16x8*>(bb + boff[ni]);
    #pragma unroll
    for (int mi = 0; mi < 4; ++mi)
      #pragma unroll
      for (int ni = 0; ni < 4; ++ni)
        acc[mi][ni] = __builtin_amdgcn_mfma_f32_16x16x32_bf16(af[mi], bf[ni], acc[mi][ni], 0, 0, 0);

    __builtin_amdgcn_sched_barrier(0);   // reads retired (MFMA lgkm waits) before signal
    __builtin_amdgcn_s_barrier();        // all waves done reading buf[cur]
  }

  // ---- epilogue: per-wave LDS stage (64x68 u16) -> coalesced stores ----
  if (m0 + wr * 64 < mend) {
    u16* cs = SM + wid * 4352;
    const float* bias = Wb + s * DD;
    #pragma unroll
    for (int ni = 0; ni < 4; ++ni) {
      const float bv = bias[n0 + wc * 64 + ni * 16 + lr];
      #pragma unroll
      for (int mi = 0; mi < 4; ++mi) {
        #pragma unroll
        for (int i = 0; i < 4; ++i)
          cs[(mi * 16 + kq * 4 + i) * 68 + ni * 16 + lr] = f2bf(acc[mi][ni][i] + bv);
      }
    }
    asm volatile("s_waitcnt lgkmcnt(0)" ::: "memory");   // cross-lane LDS visibility
    __builtin_amdgcn_sched_barrier(0);
    const int rl = lane >> 3, ch = lane & 7;
    #pragma unroll
    for (int it = 0; it < 8; ++it) {
      const int row = it * 8 + rl;
      bf16x8 v = *reinterpret_cast<const bf16x8*>(cs + row * 68 + ch * 8);
      *reinterpret_cast<bf16x8*>(pred + (size_t)(m0 + wr * 64 + row) * DD
                                 + n0 + wc * 64 + ch * 8) = v;
    }
  }
}

// ---------------- dots + logsumexp + argmax + lookback final reduction ----------------
__global__ __launch_bounds__(256) void k_dots(const u16* __restrict__ pred,
                                              const u8* __restrict__ enc8,
                                              const int* __restrict__ kidx,
                                              float* __restrict__ ploss,
                                              float* __restrict__ pcorr,
                                              unsigned* __restrict__ cnt,
                                              float* __restrict__ out) {
  const int wid  = threadIdx.x >> 6;
  const int lane = threadIdx.x & 63;
  const int p    = blockIdx.x * 4 + wid;

  const u16* prow = pred + (size_t)p * DD + lane * 4;
  float pr[20];
  #pragma unroll
  for (int j = 0; j < 5; ++j) {
    ushort4 v = *reinterpret_cast<const ushort4*>(prow + j * 256);
    pr[j * 4 + 0] = bf2f(v.x);
    pr[j * 4 + 1] = bf2f(v.y);
    pr[j * 4 + 2] = bf2f(v.z);
    pr[j * 4 + 3] = bf2f(v.w);
  }

  float dots[NK];
  #pragma unroll
  for (int kb = 0; kb < NK; kb += 5) {
    const int nb = (NK - kb < 5) ? (NK - kb) : 5;   // 5,5,5,2
    unsigned eu[5][5];
    #pragma unroll
    for (int kk = 0; kk < 5; ++kk)
      if (kk < nb) {
        const u8* erow = enc8 + (size_t)kidx[p * NK + kb + kk] * DD + lane * 4;
        #pragma unroll
        for (int j = 0; j < 5; ++j)
          eu[kk][j] = *reinterpret_cast<const unsigned*>(erow + j * 256);
      }
    #pragma unroll
    for (int kk = 0; kk < 5; ++kk)
      if (kk < nb) {
        float sum = 0.f;
        #pragma unroll
        for (int j = 0; j < 5; ++j) {
          f32x2 lo = __builtin_amdgcn_cvt_pk_f32_fp8(eu[kk][j], false);
          f32x2 hi = __builtin_amdgcn_cvt_pk_f32_fp8(eu[kk][j], true);
          sum += pr[j * 4 + 0] * lo[0] + pr[j * 4 + 1] * lo[1]
               + pr[j * 4 + 2] * hi[0] + pr[j * 4 + 3] * hi[1];
        }
        #pragma unroll
        for (int off = 32; off >= 1; off >>= 1) sum += __shfl_xor(sum, off, 64);
        dots[kb + kk] = sum;
      }
  }

  float mx = dots[0];
  #pragma unroll
  for (int k = 1; k < NK; ++k) mx = fmaxf(mx, dots[k]);
  float se = 0.f;
  #pragma unroll
  for (int k = 0; k < NK; ++k) se += __expf(dots[k] - mx);
  const float loss = __logf(se) + mx - dots[0];
  const float corr = (dots[0] == mx) ? 1.f : 0.f;

  __shared__ float sl[4], sc[4];
  __shared__ int last;
  if (lane == 0) { sl[wid] = loss; sc[wid] = corr; }
  __syncthreads();
  if (threadIdx.x == 0) {
    const float L = sl[0] + sl[1] + sl[2] + sl[3];
    const float C = sc[0] + sc[1] + sc[2] + sc[3];
    __hip_atomic_store(&ploss[blockIdx.x], L, __ATOMIC_RELAXED, __HIP_MEMORY_SCOPE_AGENT);
    __hip_atomic_store(&pcorr[blockIdx.x], C, __ATOMIC_RELAXED, __HIP_MEMORY_SCOPE_AGENT);
    const unsigned prev =
        __hip_atomic_fetch_add(cnt, 1u, __ATOMIC_ACQ_REL, __HIP_MEMORY_SCOPE_AGENT);
    last = (prev == NBLK - 1);
  }
  __syncthreads();
  if (!last) return;

  // ---- last block: reduce 2240 partials (same order as old k_red) ----
  float l = 0.f, c = 0.f;
  for (int i = threadIdx.x; i < NBLK; i += 256) {
    l += __hip_atomic_load(&ploss[i], __ATOMIC_RELAXED, __HIP_MEMORY_SCOPE_AGENT);
    c += __hip_atomic_load(&pcorr[i], __ATOMIC_RELAXED, __HIP_MEMORY_SCOPE_AGENT);
  }
  #pragma unroll
  for (int off = 32; off >= 1; off >>= 1) {
    l += __shfl_xor(l, off, 64);
    c += __shfl_xor(c, off, 64);
  }
  if (lane == 0) { sl[wid] = l; sc[wid] = c; }
  __syncthreads();
  if (threadIdx.x == 0) {
    out[0] = (sl[0] + sl[1] + sl[2] + sl[3]) * (1.0f / PP);
    out[1] = (sc[0] + sc[1] + sc[2] + sc[3]) * (1.0f / PP);
  }
}

extern "C" void kernel_launch(void* const* d_in, const int* in_sizes, int n_in,
                              void* d_out, int out_size, void* d_ws, size_t ws_size,
                              hipStream_t stream) {
  (void)in_sizes; (void)n_in; (void)out_size; (void)ws_size;

  const float* ctx_f = (const float*)d_in[0];
  const float* enc_f = (const float*)d_in[1];
  const float* Ww    = (const float*)d_in[2];
  const float* Wb    = (const float*)d_in[3];
  const int*   cidx  = (const int*)d_in[4];
  const int*   kidx  = (const int*)d_in[5];
  float* out = (float*)d_out;

  char* ws = (char*)d_ws;
  u16* ctx_bf = (u16*)(ws);
  u8*  enc_f8 = (u8*)(ws + 8028160);     // 4,014,080 B (fp8)
  u16* W_bf   = (u16*)(ws + 16056320);
  u16* pred   = (u16*)(ws + 32440320);   // 22,937,600 B
  float* ploss = (float*)(ws + 55377920);              // 8,960 B
  float* pcorr = (float*)(ws + 55377920 + 8960);       // 8,960 B
  unsigned* cnt = (unsigned*)(ws + 55377920 + 17920);  // 4 B lookback counter

  k_cvt<<<dim3(11920), 256, 0, stream>>>(ctx_f, Ww, ctx_bf, W_bf, cnt);

  k_gemm<<<dim3(4630), 256, 0, stream>>>(ctx_bf, W_bf, Wb, cidx, pred, enc_f, enc_f8);

  k_dots<<<dim3(NBLK), 256, 0, stream>>>(pred, enc_f8, kidx, ploss, pcorr, cnt, out);
}

// Round 12
// 166.119 us; speedup vs baseline: 1.1844x; 1.1844x over previous
//
#include <hip/hip_runtime.h>

#define DD 1280
#define PP 8960
#define NK 17
#define NCTX 4014080   // B*G*G*D = 64*49*1280
#define NW   8192000   // S*D*D = 5*1280*1280
#define NBLK 2240      // k_dots blocks (4 samples each)

typedef __attribute__((ext_vector_type(8))) short bf16x8;
typedef __attribute__((ext_vector_type(4))) float f32x4;
typedef __attribute__((ext_vector_type(2))) float f32x2;
typedef unsigned short u16;
typedef unsigned char u8;

__device__ __forceinline__ u16 f2bf(float f) {
  union { float f; unsigned u; } v; v.f = f;
  unsigned r = v.u + 0x7fffu + ((v.u >> 16) & 1u);  // RNE
  return (u16)(r >> 16);
}
__device__ __forceinline__ float bf2f(u16 h) {
  union { unsigned u; float f; } v; v.u = ((unsigned)h) << 16;
  return v.f;
}

__device__ __forceinline__ void gload16(const u16* g, const u16* l) {
  __builtin_amdgcn_global_load_lds(
      (const __attribute__((address_space(1))) unsigned*)g,
      (__attribute__((address_space(3))) unsigned*)l, 16, 0, 0);
}

// ---------------- fused convert: ctx->bf16 | enc->fp8 e4m3 | W->bf16 (R8-exact) ----------------
__global__ __launch_bounds__(256) void k_cvt3(const float* __restrict__ ctx,
                                              const float* __restrict__ enc,
                                              const float* __restrict__ Ww,
                                              u16* __restrict__ ctx_bf,
                                              u8*  __restrict__ enc_f8,
                                              u16* __restrict__ W_bf) {
  const int b = blockIdx.x;
  if (b >= 3920 && b < 7840) {           // enc -> fp8 e4m3 (OCP), RNE
    const int i = ((b - 3920) * 256 + threadIdx.x) * 4;
    float4 v = *reinterpret_cast<const float4*>(enc + i);
    unsigned u = __builtin_amdgcn_cvt_pk_fp8_f32(v.x, v.y, 0u, false);
    u = __builtin_amdgcn_cvt_pk_fp8_f32(v.z, v.w, u, true);
    *reinterpret_cast<unsigned*>(enc_f8 + i) = u;
    return;
  }
  const float* src; u16* dst; int i;
  if (b < 3920) { src = ctx; dst = ctx_bf; i = (b * 256 + threadIdx.x) * 4; }
  else          { src = Ww;  dst = W_bf;   i = ((b - 7840) * 256 + threadIdx.x) * 4; }
  float4 v = *reinterpret_cast<const float4*>(src + i);
  ushort4 o;
  o.x = f2bf(v.x); o.y = f2bf(v.y); o.z = f2bf(v.z); o.w = f2bf(v.w);
  *reinterpret_cast<ushort4*>(dst + i) = o;
}

// ---------------- gathered GEMM, 128x128, counted-vmcnt double-buffer (R8-exact) ----------------
__global__ __launch_bounds__(256) void k_gemm(const u16* __restrict__ ctx,
                                              const u16* __restrict__ W,
                                              const float* __restrict__ Wb,
                                              const int* __restrict__ cidx,
                                              u16* __restrict__ pred) {
  // SM layout (u16): A buf b = [b*4096, +4096) ; B buf b = [8192 + b*4096, +4096)
  // epilogue Csm wave w = [w*4352, +4352)
  __shared__ u16 SM[17408];

  const int id  = blockIdx.x;            // 0..709, bijective XCD swizzle (m204)
  const int xcd = id & 7, pos = id >> 3;
  const int wgid = (xcd < 6) ? (xcd * 89 + pos) : (534 + (xcd - 6) * 88 + pos);
  const int bx = wgid / 10;
  const int by = wgid - bx * 10;

  int s, mt0, off, mend;
  if (bx < 21)      { s = 0; mt0 = 0;  off = 0;    mend = 2688; }
  else if (bx < 39) { s = 1; mt0 = 21; off = 2688; mend = 4928; }
  else if (bx < 53) { s = 2; mt0 = 39; off = 4928; mend = 6720; }
  else if (bx < 64) { s = 3; mt0 = 53; off = 6720; mend = 8064; }
  else              { s = 4; mt0 = 64; off = 8064; mend = 8960; }
  const int m0 = off + (bx - mt0) * 128;
  const int n0 = by * 128;

  const int t = threadIdx.x;
  const int lane = t & 63, wid = t >> 6;
  const int wr = wid >> 1, wc = wid & 1;
  const int lr = lane & 15, kq = lane >> 4;

  // staging: 512 slots of 16B per tile; slot = g*256 + t; row = slot>>2, chunk = slot&3
  const int r0s = t >> 2, c0 = t & 3;
  const int r1s = 64 + r0s;
  const int cs0 = c0 ^ ((r0s >> 1) & 3);
  const int cs1 = c0 ^ ((r1s >> 1) & 3);
  int ar0 = m0 + r0s; if (ar0 > mend - 1) ar0 = mend - 1;
  int ar1 = m0 + r1s; if (ar1 > mend - 1) ar1 = mend - 1;
  const u16* aptr0 = ctx + (size_t)cidx[ar0] * DD + cs0 * 8;
  const u16* aptr1 = ctx + (size_t)cidx[ar1] * DD + cs1 * 8;
  const u16* bbase = W + (size_t)s * DD * DD;
  const u16* bptr0 = bbase + (size_t)(n0 + r0s) * DD + cs0 * 8;
  const u16* bptr1 = bbase + (size_t)(n0 + r1s) * DD + cs1 * 8;
  const int sl0 = wid * 512;             // wave-uniform u16 offset within a buffer
  const int sl1 = 2048 + wid * 512;

  f32x4 acc[4][4];
  #pragma unroll
  for (int i = 0; i < 4; ++i)
    #pragma unroll
    for (int j = 0; j < 4; ++j)
      acc[i][j] = (f32x4){0.f, 0.f, 0.f, 0.f};

  // loop-invariant ds_read offsets (u16 units within one buffer)
  int aoff[4], boff[4];
  #pragma unroll
  for (int mi = 0; mi < 4; ++mi) {
    const int ra = wr * 64 + mi * 16 + lr;
    aoff[mi] = ra * 32 + (kq ^ ((ra >> 1) & 3)) * 8;
  }
  #pragma unroll
  for (int ni = 0; ni < 4; ++ni) {
    const int rb = wc * 64 + ni * 16 + lr;
    boff[ni] = rb * 32 + (kq ^ ((rb >> 1) & 3)) * 8;
  }

  // prologue: stage tile 0 into buf 0
  gload16(aptr0, SM + sl0); gload16(aptr1, SM + sl1);
  gload16(bptr0, SM + 8192 + sl0); gload16(bptr1, SM + 8192 + sl1);

  #pragma unroll 2
  for (int kt = 0; kt < 40; ++kt) {
    const int cur = kt & 1;
    if (kt < 39) {
      const int k0 = (kt + 1) * 32;
      const int d = (cur ^ 1) * 4096;
      gload16(aptr0 + k0, SM + d + sl0); gload16(aptr1 + k0, SM + d + sl1);
      gload16(bptr0 + k0, SM + 8192 + d + sl0); gload16(bptr1 + k0, SM + 8192 + d + sl1);
      asm volatile("s_waitcnt vmcnt(4)" ::: "memory");   // tile kt landed; kt+1 in flight
    } else {
      asm volatile("s_waitcnt vmcnt(0)" ::: "memory");
    }
    __builtin_amdgcn_s_barrier();        // all waves: tile kt visible
    __builtin_amdgcn_sched_barrier(0);

    const u16* ab = SM + cur * 4096;
    const u16* bb = SM + 8192 + cur * 4096;
    bf16x8 af[4], bf[4];
    #pragma unroll
    for (int mi = 0; mi < 4; ++mi)
      af[mi] = *reinterpret_cast<const bf16x8*>(ab + aoff[mi]);
    #pragma unroll
    for (int ni = 0; ni < 4; ++ni)
      bf[ni] = *reinterpret_cast<const bf16x8*>(bb + boff[ni]);
    #pragma unroll
    for (int mi = 0; mi < 4; ++mi)
      #pragma unroll
      for (int ni = 0; ni < 4; ++ni)
        acc[mi][ni] = __builtin_amdgcn_mfma_f32_16x16x32_bf16(af[mi], bf[ni], acc[mi][ni], 0, 0, 0);

    __builtin_amdgcn_sched_barrier(0);   // reads retired (MFMA lgkm waits) before signal
    __builtin_amdgcn_s_barrier();        // all waves done reading buf[cur]
  }

  // ---- epilogue: per-wave LDS stage (64x68 u16) -> coalesced stores ----
  if (m0 + wr * 64 < mend) {
    u16* cs = SM + wid * 4352;
    const float* bias = Wb + s * DD;
    #pragma unroll
    for (int ni = 0; ni < 4; ++ni) {
      const float bv = bias[n0 + wc * 64 + ni * 16 + lr];
      #pragma unroll
      for (int mi = 0; mi < 4; ++mi) {
        #pragma unroll
        for (int i = 0; i < 4; ++i)
          cs[(mi * 16 + kq * 4 + i) * 68 + ni * 16 + lr] = f2bf(acc[mi][ni][i] + bv);
      }
    }
    asm volatile("s_waitcnt lgkmcnt(0)" ::: "memory");   // cross-lane LDS visibility
    __builtin_amdgcn_sched_barrier(0);
    const int rl = lane >> 3, ch = lane & 7;
    #pragma unroll
    for (int it = 0; it < 8; ++it) {
      const int row = it * 8 + rl;
      bf16x8 v = *reinterpret_cast<const bf16x8*>(cs + row * 68 + ch * 8);
      *reinterpret_cast<bf16x8*>(pred + (size_t)(m0 + wr * 64 + row) * DD
                                 + n0 + wc * 64 + ch * 8) = v;
    }
  }
}

// ---------------- dots: all-kidx-upfront + software-pipelined gather batches ----------------
// 1 wave/sample, 4 samples/block. Batches {5,5,5,2}; batch b+1's 25 gather dwords
// issue before batch b is processed (double-buffered eu, fully static indexing).
__global__ __launch_bounds__(256) void k_dots(const u16* __restrict__ pred,
                                              const u8* __restrict__ enc8,
                                              const int* __restrict__ kidx,
                                              float* __restrict__ ploss,
                                              float* __restrict__ pcorr) {
  const int wid  = threadIdx.x >> 6;
  const int lane = threadIdx.x & 63;
  const int p    = blockIdx.x * 4 + wid;

  // all 17 candidate indices up front: one load latency, not one per batch
  int ki[NK];
  #pragma unroll
  for (int k = 0; k < NK; ++k) ki[k] = kidx[p * NK + k];

  const u16* prow = pred + (size_t)p * DD + lane * 4;
  float pr[20];
  #pragma unroll
  for (int j = 0; j < 5; ++j) {
    ushort4 v = *reinterpret_cast<const ushort4*>(prow + j * 256);
    pr[j * 4 + 0] = bf2f(v.x);
    pr[j * 4 + 1] = bf2f(v.y);
    pr[j * 4 + 2] = bf2f(v.z);
    pr[j * 4 + 3] = bf2f(v.w);
  }

  float dots[NK];
  unsigned eu[2][5][5];

  // prologue: issue batch 0 gathers
  #pragma unroll
  for (int kk = 0; kk < 5; ++kk) {
    const u8* erow = enc8 + (size_t)ki[kk] * DD + lane * 4;
    #pragma unroll
    for (int j = 0; j < 5; ++j)
      eu[0][kk][j] = *reinterpret_cast<const unsigned*>(erow + j * 256);
  }

  #pragma unroll
  for (int kb = 0; kb < 4; ++kb) {                 // fully unrolled -> static eu indices
    const int base = kb * 5;
    const int nb  = (kb == 3) ? 2 : 5;
    if (kb < 3) {                                  // prefetch batch kb+1
      const int nnb = (kb == 2) ? 2 : 5;
      #pragma unroll
      for (int kk = 0; kk < 5; ++kk)
        if (kk < nnb) {
          const u8* erow = enc8 + (size_t)ki[base + 5 + kk] * DD + lane * 4;
          #pragma unroll
          for (int j = 0; j < 5; ++j)
            eu[(kb + 1) & 1][kk][j] = *reinterpret_cast<const unsigned*>(erow + j * 256);
        }
    }
    #pragma unroll
    for (int kk = 0; kk < 5; ++kk)
      if (kk < nb) {
        float sum = 0.f;
        #pragma unroll
        for (int j = 0; j < 5; ++j) {
          f32x2 lo = __builtin_amdgcn_cvt_pk_f32_fp8(eu[kb & 1][kk][j], false);
          f32x2 hi = __builtin_amdgcn_cvt_pk_f32_fp8(eu[kb & 1][kk][j], true);
          sum += pr[j * 4 + 0] * lo[0] + pr[j * 4 + 1] * lo[1]
               + pr[j * 4 + 2] * hi[0] + pr[j * 4 + 3] * hi[1];
        }
        #pragma unroll
        for (int off = 32; off >= 1; off >>= 1) sum += __shfl_xor(sum, off, 64);
        dots[base + kk] = sum;
      }
  }

  float mx = dots[0];
  #pragma unroll
  for (int k = 1; k < NK; ++k) mx = fmaxf(mx, dots[k]);
  float se = 0.f;
  #pragma unroll
  for (int k = 0; k < NK; ++k) se += __expf(dots[k] - mx);
  const float loss = __logf(se) + mx - dots[0];
  const float corr = (dots[0] == mx) ? 1.f : 0.f;

  __shared__ float sl[4], sc[4];
  if (lane == 0) { sl[wid] = loss; sc[wid] = corr; }
  __syncthreads();
  if (threadIdx.x == 0) {
    ploss[blockIdx.x] = sl[0] + sl[1] + sl[2] + sl[3];
    pcorr[blockIdx.x] = sc[0] + sc[1] + sc[2] + sc[3];
  }
}

// ---------------- final reduction: 2240 partials -> out[0..1] ----------------
__global__ __launch_bounds__(256) void k_red(const float* __restrict__ ploss,
                                             const float* __restrict__ pcorr,
                                             float* __restrict__ out) {
  float l = 0.f, c = 0.f;
  for (int i = threadIdx.x; i < NBLK; i += 256) { l += ploss[i]; c += pcorr[i]; }
  #pragma unroll
  for (int off = 32; off >= 1; off >>= 1) {
    l += __shfl_xor(l, off, 64);
    c += __shfl_xor(c, off, 64);
  }
  __shared__ float sl[4], sc[4];
  const int wid = threadIdx.x >> 6, lane = threadIdx.x & 63;
  if (lane == 0) { sl[wid] = l; sc[wid] = c; }
  __syncthreads();
  if (threadIdx.x == 0) {
    out[0] = (sl[0] + sl[1] + sl[2] + sl[3]) * (1.0f / PP);
    out[1] = (sc[0] + sc[1] + sc[2] + sc[3]) * (1.0f / PP);
  }
}

extern "C" void kernel_launch(void* const* d_in, const int* in_sizes, int n_in,
                              void* d_out, int out_size, void* d_ws, size_t ws_size,
                              hipStream_t stream) {
  (void)in_sizes; (void)n_in; (void)out_size; (void)ws_size;

  const float* ctx_f = (const float*)d_in[0];
  const float* enc_f = (const float*)d_in[1];
  const float* Ww    = (const float*)d_in[2];
  const float* Wb    = (const float*)d_in[3];
  const int*   cidx  = (const int*)d_in[4];
  const int*   kidx  = (const int*)d_in[5];
  float* out = (float*)d_out;

  char* ws = (char*)d_ws;
  u16* ctx_bf = (u16*)(ws);
  u8*  enc_f8 = (u8*)(ws + 8028160);     // 4,014,080 B (fp8)
  u16* W_bf   = (u16*)(ws + 16056320);
  u16* pred   = (u16*)(ws + 32440320);   // 22,937,600 B
  float* ploss = (float*)(ws + 55377920);            // 8,960 B
  float* pcorr = (float*)(ws + 55377920 + 8960);     // 8,960 B

  k_cvt3<<<dim3(15840), 256, 0, stream>>>(ctx_f, enc_f, Ww, ctx_bf, enc_f8, W_bf);

  k_gemm<<<dim3(710), 256, 0, stream>>>(ctx_bf, W_bf, Wb, cidx, pred);

  k_dots<<<dim3(NBLK), 256, 0, stream>>>(pred, enc_f8, kidx, ploss, pcorr);

  k_red<<<dim3(1), 256, 0, stream>>>(ploss, pcorr, out);
}